// Round 1
// baseline (831.430 us; speedup 1.0000x reference)
//
#include <hip/hip_runtime.h>
#include <math.h>

#define BATCH   4
#define SEQ     2048
#define DMODEL  512
#define NHEADS  8
#define HDIM    64
#define QKV_N   (3*DMODEL)   // 1536

// ---------------------------------------------------------------------------
// GEMM A: qkv = x @ W_qkv  (M=8192, N=1536, K=512), epilogue scatters into
// contiguous Q,K,V [B,H,S,64] applying the reference's flat-reinterpret
// "scramble": n = s*8 + h  ->  h' = n>>11, s' = n&2047.
// ---------------------------------------------------------------------------
__global__ __launch_bounds__(256) void gemm_qkv(
    const float* __restrict__ X,      // [B*S, 512]
    const float* __restrict__ W,      // [512, 1536]
    float* __restrict__ Qb, float* __restrict__ Kb, float* __restrict__ Vb)
{
  __shared__ float As[16][68];   // [k][m], padded
  __shared__ float Bs[16][64];   // [k][n]
  const int t  = threadIdx.x;
  const int tx = t & 15, ty = t >> 4;
  const int m0 = blockIdx.y << 6;
  const int n0 = blockIdx.x << 6;
  float acc[4][4] = {};
  for (int k0 = 0; k0 < DMODEL; k0 += 16) {
    {
      const int row = t >> 2, seg = (t & 3) << 2;
      const float4 v = *reinterpret_cast<const float4*>(X + (size_t)(m0+row)*DMODEL + k0 + seg);
      As[seg+0][row] = v.x; As[seg+1][row] = v.y; As[seg+2][row] = v.z; As[seg+3][row] = v.w;
    }
    {
      const int kr = t >> 4, seg = (t & 15) << 2;
      *reinterpret_cast<float4*>(&Bs[kr][seg]) =
          *reinterpret_cast<const float4*>(W + (size_t)(k0+kr)*QKV_N + n0 + seg);
    }
    __syncthreads();
#pragma unroll
    for (int k = 0; k < 16; ++k) {
      const float4 a  = *reinterpret_cast<const float4*>(&As[k][ty<<2]);
      const float4 bq = *reinterpret_cast<const float4*>(&Bs[k][tx<<2]);
      const float av[4] = {a.x,a.y,a.z,a.w};
      const float bv[4] = {bq.x,bq.y,bq.z,bq.w};
#pragma unroll
      for (int i=0;i<4;++i)
#pragma unroll
        for (int j=0;j<4;++j) acc[i][j] += av[i]*bv[j];
    }
    __syncthreads();
  }
  // scatter epilogue
#pragma unroll
  for (int i=0;i<4;++i) {
    const int m = m0 + (ty<<2) + i;
    const int b = m >> 11, s = m & 2047;
#pragma unroll
    for (int j=0;j<4;++j) {
      const int c   = n0 + (tx<<2) + j;
      const int h   = c / 192;
      const int e   = c - h*192;
      const int n   = (s<<3) + h;
      const int hp  = n >> 11, sp = n & 2047;
      const size_t idx = (((size_t)((b<<3) + hp) * SEQ + sp) * HDIM) + (e & 63);
      float* dst = (e < 64) ? Qb : ((e < 128) ? Kb : Vb);
      dst[idx] = acc[i][j];
    }
  }
}

// ---------------------------------------------------------------------------
// Flash attention, fp32. One block = 64 queries of one (b,h'). Online softmax.
// Mask indexes raw scrambled positions. Rows with no valid key -> 0.
// ---------------------------------------------------------------------------
__global__ __launch_bounds__(256) void attn(
    const float* __restrict__ Q,   // [B*H, S, 64]
    const float* __restrict__ K,
    const float* __restrict__ V,
    const int* __restrict__ mask,  // [B, S] (0/1)
    float* __restrict__ O)         // [B*H, S, 64]
{
  __shared__ float Qs [64][68];  // [d][q] transposed
  __shared__ float KPs[64][68];  // union: K as [d][k], later P as [q][k]
  __shared__ float Vs [64][68];  // [k][d]
  const int t  = threadIdx.x;
  const int tx = t & 15, ty = t >> 4;
  const int bh = blockIdx.y;
  const int b  = bh >> 3;
  const int q0 = blockIdx.x << 6;
  const float* Qbase = Q + ((size_t)bh * SEQ + q0) * HDIM;
  const float* Kbase = K + (size_t)bh * SEQ * HDIM;
  const float* Vbase = V + (size_t)bh * SEQ * HDIM;
  const int*   mb    = mask + b * SEQ;

  // load Q tile transposed
  for (int i = t; i < 64*16; i += 256) {
    const int r  = i >> 4;
    const int cg = (i & 15) << 2;
    const float4 v = *reinterpret_cast<const float4*>(Qbase + r*HDIM + cg);
    Qs[cg+0][r] = v.x; Qs[cg+1][r] = v.y; Qs[cg+2][r] = v.z; Qs[cg+3][r] = v.w;
  }

  float m_run[4], l_run[4], o[4][4] = {};
#pragma unroll
  for (int i=0;i<4;++i) { m_run[i] = -INFINITY; l_run[i] = 0.f; }

  for (int kt = 0; kt < SEQ; kt += 64) {
    __syncthreads();                     // (A) prev-iter LDS consumers done
    for (int i = t; i < 64*16; i += 256) {
      const int r  = i >> 4;
      const int cg = (i & 15) << 2;
      const float4 kv = *reinterpret_cast<const float4*>(Kbase + (size_t)(kt + r)*HDIM + cg);
      KPs[cg+0][r] = kv.x; KPs[cg+1][r] = kv.y; KPs[cg+2][r] = kv.z; KPs[cg+3][r] = kv.w;
      *reinterpret_cast<float4*>(&Vs[r][cg]) =
          *reinterpret_cast<const float4*>(Vbase + (size_t)(kt + r)*HDIM + cg);
    }
    __syncthreads();                     // (B) tiles visible

    float sc[4][4] = {};
#pragma unroll 8
    for (int d = 0; d < 64; ++d) {
      const float4 qv = *reinterpret_cast<const float4*>(&Qs [d][ty<<2]);
      const float4 kv = *reinterpret_cast<const float4*>(&KPs[d][tx<<2]);
      const float qa[4] = {qv.x,qv.y,qv.z,qv.w};
      const float ka[4] = {kv.x,kv.y,kv.z,kv.w};
#pragma unroll
      for (int i=0;i<4;++i)
#pragma unroll
        for (int j=0;j<4;++j) sc[i][j] += qa[i]*ka[j];
    }

    bool vk[4];
#pragma unroll
    for (int j=0;j<4;++j) vk[j] = (mb[kt + (tx<<2) + j] != 0);

    float p[4][4];
#pragma unroll
    for (int i=0;i<4;++i) {
      float mt = -INFINITY;
#pragma unroll
      for (int j=0;j<4;++j) {
        sc[i][j] = vk[j] ? sc[i][j]*0.125f : -INFINITY;
        mt = fmaxf(mt, sc[i][j]);
      }
      for (int off=1; off<16; off<<=1) mt = fmaxf(mt, __shfl_xor(mt, off));
      const float mnew  = fmaxf(m_run[i], mt);
      const float alpha = (mnew == -INFINITY) ? 1.f : __expf(m_run[i] - mnew);
      float rs = 0.f;
#pragma unroll
      for (int j=0;j<4;++j) {
        const float pv = vk[j] ? __expf(sc[i][j] - mnew) : 0.f;
        p[i][j] = pv; rs += pv;
      }
      for (int off=1; off<16; off<<=1) rs += __shfl_xor(rs, off);
      l_run[i] = l_run[i]*alpha + rs;
      m_run[i] = mnew;
#pragma unroll
      for (int j=0;j<4;++j) o[i][j] *= alpha;
    }
    __syncthreads();                     // (C) done reading KPs as K
#pragma unroll
    for (int i=0;i<4;++i)
      *reinterpret_cast<float4*>(&KPs[(ty<<2)+i][tx<<2]) =
          make_float4(p[i][0], p[i][1], p[i][2], p[i][3]);
    __syncthreads();                     // (D) P visible

#pragma unroll 8
    for (int k = 0; k < 64; ++k) {
      const float4 vv = *reinterpret_cast<const float4*>(&Vs[k][tx<<2]);
      const float va[4] = {vv.x,vv.y,vv.z,vv.w};
      float pa[4];
#pragma unroll
      for (int i=0;i<4;++i) pa[i] = KPs[(ty<<2)+i][k];
#pragma unroll
      for (int i=0;i<4;++i)
#pragma unroll
        for (int j=0;j<4;++j) o[i][j] += pa[i]*va[j];
    }
  }

  float* Obase = O + ((size_t)bh * SEQ + q0) * HDIM;
#pragma unroll
  for (int i=0;i<4;++i) {
    const int q  = (ty<<2) + i;
    const bool qv = (mb[q0 + q] != 0);
    const float inv = (qv && l_run[i] > 0.f) ? 1.f / l_run[i] : 0.f;
    const float4 ov = make_float4(o[i][0]*inv, o[i][1]*inv, o[i][2]*inv, o[i][3]*inv);
    *reinterpret_cast<float4*>(Obase + (size_t)q*HDIM + (tx<<2)) = ov;
  }
}

// ---------------------------------------------------------------------------
// GEMM C: out = O @ W_out  (M=8192, N=512, K=512). O read flat as [B*S,512]
// (the reference's final reshape is a free reinterpret of our O layout).
// ---------------------------------------------------------------------------
__global__ __launch_bounds__(256) void gemm_out(
    const float* __restrict__ X,   // [B*S, 512]
    const float* __restrict__ W,   // [512, 512]
    float* __restrict__ Out)       // [B*S, 512]
{
  __shared__ float As[16][68];
  __shared__ float Bs[16][64];
  const int t  = threadIdx.x;
  const int tx = t & 15, ty = t >> 4;
  const int m0 = blockIdx.y << 6;
  const int n0 = blockIdx.x << 6;
  float acc[4][4] = {};
  for (int k0 = 0; k0 < DMODEL; k0 += 16) {
    {
      const int row = t >> 2, seg = (t & 3) << 2;
      const float4 v = *reinterpret_cast<const float4*>(X + (size_t)(m0+row)*DMODEL + k0 + seg);
      As[seg+0][row] = v.x; As[seg+1][row] = v.y; As[seg+2][row] = v.z; As[seg+3][row] = v.w;
    }
    {
      const int kr = t >> 4, seg = (t & 15) << 2;
      *reinterpret_cast<float4*>(&Bs[kr][seg]) =
          *reinterpret_cast<const float4*>(W + (size_t)(k0+kr)*DMODEL + n0 + seg);
    }
    __syncthreads();
#pragma unroll
    for (int k = 0; k < 16; ++k) {
      const float4 a  = *reinterpret_cast<const float4*>(&As[k][ty<<2]);
      const float4 bq = *reinterpret_cast<const float4*>(&Bs[k][tx<<2]);
      const float av[4] = {a.x,a.y,a.z,a.w};
      const float bv[4] = {bq.x,bq.y,bq.z,bq.w};
#pragma unroll
      for (int i=0;i<4;++i)
#pragma unroll
        for (int j=0;j<4;++j) acc[i][j] += av[i]*bv[j];
    }
    __syncthreads();
  }
#pragma unroll
  for (int i=0;i<4;++i) {
    const int m = m0 + (ty<<2) + i;
    *reinterpret_cast<float4*>(Out + (size_t)m*DMODEL + n0 + (tx<<2)) =
        make_float4(acc[i][0], acc[i][1], acc[i][2], acc[i][3]);
  }
}

// ---------------------------------------------------------------------------
extern "C" void kernel_launch(void* const* d_in, const int* in_sizes, int n_in,
                              void* d_out, int out_size, void* d_ws, size_t ws_size,
                              hipStream_t stream) {
  (void)in_sizes; (void)n_in; (void)out_size; (void)ws_size;
  const float* x     = (const float*)d_in[0];
  // d_in[1]: dense mask, unused by reference path
  const int*   pmask = (const int*)d_in[2];
  const float* Wqkv  = (const float*)d_in[3];
  const float* Wout  = (const float*)d_in[4];
  float* out = (float*)d_out;

  const size_t per = (size_t)BATCH * NHEADS * SEQ * HDIM;  // 4,194,304 floats
  float* Qb = (float*)d_ws;
  float* Kb = Qb + per;
  float* Vb = Kb + per;
  float* Ob = Vb + per;   // total 64 MiB of workspace

  dim3 gA(QKV_N/64, (BATCH*SEQ)/64);   // 24 x 128
  gemm_qkv<<<gA, 256, 0, stream>>>(x, Wqkv, Qb, Kb, Vb);

  dim3 gAt(SEQ/64, BATCH*NHEADS);      // 32 x 32
  attn<<<gAt, 256, 0, stream>>>(Qb, Kb, Vb, pmask, Ob);

  dim3 gC(DMODEL/64, (BATCH*SEQ)/64);  // 8 x 128
  gemm_out<<<gC, 256, 0, stream>>>(Ob, Wout, out);
}

// Round 2
// 339.979 us; speedup vs baseline: 2.4455x; 2.4455x over previous
//
#include <hip/hip_runtime.h>
#include <math.h>
#include <stdint.h>

#define BATCH   4
#define SEQ     2048
#define DMODEL  512
#define NHEADS  8
#define HDIM    64
#define QKV_N   (3*DMODEL)   // 1536

typedef short bf8  __attribute__((ext_vector_type(8)));   // 8 bf16 (4 VGPRs)
typedef float f32x4 __attribute__((ext_vector_type(4)));  // 4 fp32 acc

#define MFMA16(a,b,c) __builtin_amdgcn_mfma_f32_16x16x32_bf16((a),(b),(c),0,0,0)

__device__ inline unsigned short f2bf(float f){      // RNE fp32->bf16
  unsigned int u = __float_as_uint(f);
  u += 0x7FFFu + ((u >> 16) & 1u);
  return (unsigned short)(u >> 16);
}

// ---------------------------------------------------------------------------
// x [8192*512] fp32 -> bf16
// ---------------------------------------------------------------------------
__global__ __launch_bounds__(256) void cast_x(const float* __restrict__ in,
                                              unsigned short* __restrict__ out){
  const int i = blockIdx.x*256 + threadIdx.x;          // 524288 groups of 8
  const float4 a = reinterpret_cast<const float4*>(in)[2*i];
  const float4 b = reinterpret_cast<const float4*>(in)[2*i+1];
  uint4 o; unsigned short* us = reinterpret_cast<unsigned short*>(&o);
  us[0]=f2bf(a.x); us[1]=f2bf(a.y); us[2]=f2bf(a.z); us[3]=f2bf(a.w);
  us[4]=f2bf(b.x); us[5]=f2bf(b.y); us[6]=f2bf(b.z); us[7]=f2bf(b.w);
  reinterpret_cast<uint4*>(out)[i] = o;
}

// ---------------------------------------------------------------------------
// out[c][r] = bf16(in[r][c])  (W^T so GEMM B-fragments are k-contiguous)
// ---------------------------------------------------------------------------
__global__ __launch_bounds__(256) void transpose_cast(
    const float* __restrict__ in, unsigned short* __restrict__ out, int R, int C){
  __shared__ unsigned short Ts[64][72];
  const int t = threadIdx.x;
  const int r0 = blockIdx.y<<6, c0 = blockIdx.x<<6;
  const int rr = t>>2, cs = (t&3)<<4;
#pragma unroll
  for (int p=0;p<4;++p){
    float4 v = *reinterpret_cast<const float4*>(in + (size_t)(r0+rr)*C + c0 + cs + p*4);
    Ts[rr][cs+p*4+0]=f2bf(v.x); Ts[rr][cs+p*4+1]=f2bf(v.y);
    Ts[rr][cs+p*4+2]=f2bf(v.z); Ts[rr][cs+p*4+3]=f2bf(v.w);
  }
  __syncthreads();
  const int cc = t>>2, rs = (t&3)<<4;
#pragma unroll
  for (int p=0;p<4;++p){
    ushort4 o;
    o.x = Ts[rs+p*4+0][cc]; o.y = Ts[rs+p*4+1][cc];
    o.z = Ts[rs+p*4+2][cc]; o.w = Ts[rs+p*4+3][cc];
    *reinterpret_cast<ushort4*>(out + (size_t)(c0+cc)*R + r0 + rs + p*4) = o;
  }
}

// ---------------------------------------------------------------------------
// MFMA GEMM A: qkv = Xh @ WqkvT^T  (M=8192,N=1536,K=512), scatter epilogue
// into bf16 Q,K,V [B*H][S][64] with the reference's flat-reinterpret scramble.
// 128x128 block tile, 4 waves, each wave 64x64 (4x4 16x16x32 frags), BK=64.
// ---------------------------------------------------------------------------
__global__ __launch_bounds__(256) void gemm_qkv_mfma(
    const unsigned short* __restrict__ A,   // [8192][512] bf16
    const unsigned short* __restrict__ Bt,  // [1536][512] bf16 (W^T)
    unsigned short* __restrict__ Qb, unsigned short* __restrict__ Kb,
    unsigned short* __restrict__ Vb)
{
  __shared__ unsigned short As[128][72];
  __shared__ unsigned short Bs[128][72];
  const int t = threadIdx.x;
  const int w = t>>6, lane = t&63, quad = lane>>4, l15 = lane&15;
  const int wr = (w>>1)<<6, wc = (w&1)<<6;
  const int m0 = blockIdx.y<<7, n0 = blockIdx.x<<7;
  const int row = t>>3, seg = t&7;
  const unsigned short* Agp = A  + (size_t)(m0+row)*DMODEL + seg*8;
  const unsigned short* Bgp = Bt + (size_t)(n0+row)*DMODEL + seg*8;
  uint4 ga[4], gb[4];
#pragma unroll
  for (int p=0;p<4;++p){
    ga[p] = *reinterpret_cast<const uint4*>(Agp + (size_t)p*32*DMODEL);
    gb[p] = *reinterpret_cast<const uint4*>(Bgp + (size_t)p*32*DMODEL);
  }
  f32x4 acc[4][4];
#pragma unroll
  for (int i=0;i<4;++i)
#pragma unroll
    for (int j=0;j<4;++j) acc[i][j] = (f32x4){0.f,0.f,0.f,0.f};

  for (int k0=0;k0<DMODEL;k0+=64){
    __syncthreads();
#pragma unroll
    for (int p=0;p<4;++p){
      *reinterpret_cast<uint4*>(&As[row+p*32][seg*8]) = ga[p];
      *reinterpret_cast<uint4*>(&Bs[row+p*32][seg*8]) = gb[p];
    }
    __syncthreads();
    if (k0+64 < DMODEL){
#pragma unroll
      for (int p=0;p<4;++p){
        ga[p] = *reinterpret_cast<const uint4*>(Agp + (size_t)p*32*DMODEL + k0+64);
        gb[p] = *reinterpret_cast<const uint4*>(Bgp + (size_t)p*32*DMODEL + k0+64);
      }
    }
#pragma unroll
    for (int ks=0;ks<2;++ks){
      bf8 af[4], bfr[4];
#pragma unroll
      for (int mi=0;mi<4;++mi)
        af[mi]  = *reinterpret_cast<const bf8*>(&As[wr+mi*16+l15][ks*32+quad*8]);
#pragma unroll
      for (int nj=0;nj<4;++nj)
        bfr[nj] = *reinterpret_cast<const bf8*>(&Bs[wc+nj*16+l15][ks*32+quad*8]);
#pragma unroll
      for (int mi=0;mi<4;++mi)
#pragma unroll
        for (int nj=0;nj<4;++nj) acc[mi][nj] = MFMA16(af[mi], bfr[nj], acc[mi][nj]);
    }
  }
  // scatter epilogue (same mapping as round-0, bf16 stores)
#pragma unroll
  for (int mi=0;mi<4;++mi){
#pragma unroll
    for (int i=0;i<4;++i){
      const int m = m0 + wr + mi*16 + quad*4 + i;
      const int bb = m>>11, s = m&2047;
#pragma unroll
      for (int nj=0;nj<4;++nj){
        const int c = n0 + wc + nj*16 + l15;
        const int h = c/192, e = c - h*192;
        const int n = (s<<3)+h;
        const int hp = n>>11, sp = n&2047;
        const size_t idx = ((size_t)((bb<<3)+hp)*SEQ + sp)*HDIM + (e&63);
        unsigned short* dst = (e<64)?Qb:((e<128)?Kb:Vb);
        dst[idx] = f2bf(acc[mi][nj][i]);
      }
    }
  }
}

// ---------------------------------------------------------------------------
// MFMA flash attention. Block = 4 waves; wave w owns 16-query strip of a
// 64-query tile of one (b,h'). QK^T frags straight from global; fp32 online
// softmax; P -> LDS (bf16, A-layout); V staged transposed [d][key] (+8 pad).
// ---------------------------------------------------------------------------
__global__ __launch_bounds__(256) void attn_mfma(
    const unsigned short* __restrict__ Q, const unsigned short* __restrict__ K,
    const unsigned short* __restrict__ V, const int* __restrict__ mask,
    unsigned short* __restrict__ O)
{
  __shared__ unsigned short Vt[64][72];      // V^T tile: [d][key]
  __shared__ unsigned short Pl[4][16][72];   // per-wave P strip [q][key]
  const int t = threadIdx.x;
  const int w = t>>6, lane = t&63, quad = lane>>4, l15 = lane&15;
  const int bh = blockIdx.y, b = bh>>3;
  const int q0 = blockIdx.x<<6;
  const int qs = q0 + w*16;
  const unsigned short* Qb = Q + (size_t)bh*SEQ*HDIM;
  const unsigned short* Kb = K + (size_t)bh*SEQ*HDIM;
  const unsigned short* Vb = V + (size_t)bh*SEQ*HDIM;
  const int* mb = mask + b*SEQ;

  bf8 qf0 = *reinterpret_cast<const bf8*>(Qb + (size_t)(qs+l15)*HDIM + quad*8);
  bf8 qf1 = *reinterpret_cast<const bf8*>(Qb + (size_t)(qs+l15)*HDIM + 32 + quad*8);

  f32x4 of[4];
  float m_run[4], l_run[4];
#pragma unroll
  for (int i=0;i<4;++i){ of[i]=(f32x4){0.f,0.f,0.f,0.f}; m_run[i]=-INFINITY; l_run[i]=0.f; }

  const int vkey = t>>2, vds = (t&3)<<4;     // V staging: key 0..63, d base

  for (int kt=0; kt<SEQ; kt+=64){
    __syncthreads();                          // prev-iter Vt/Pl readers done
    {
      uint4 v0 = *reinterpret_cast<const uint4*>(Vb + (size_t)(kt+vkey)*HDIM + vds);
      uint4 v1 = *reinterpret_cast<const uint4*>(Vb + (size_t)(kt+vkey)*HDIM + vds + 8);
      const unsigned short* u0 = reinterpret_cast<const unsigned short*>(&v0);
      const unsigned short* u1 = reinterpret_cast<const unsigned short*>(&v1);
#pragma unroll
      for (int j=0;j<8;++j) Vt[vds+j][vkey]   = u0[j];
#pragma unroll
      for (int j=0;j<8;++j) Vt[vds+8+j][vkey] = u1[j];
    }
    bool vk[4];
#pragma unroll
    for (int nf=0;nf<4;++nf) vk[nf] = (mb[kt + nf*16 + l15] != 0);
    __syncthreads();                          // Vt visible

    // S = Q K^T (16 x 64 per wave)
    f32x4 sc[4];
#pragma unroll
    for (int nf=0;nf<4;++nf){
      const unsigned short* kp = Kb + (size_t)(kt + nf*16 + l15)*HDIM;
      bf8 k0f = *reinterpret_cast<const bf8*>(kp + quad*8);
      bf8 k1f = *reinterpret_cast<const bf8*>(kp + 32 + quad*8);
      f32x4 s = (f32x4){0.f,0.f,0.f,0.f};
      s = MFMA16(qf0, k0f, s);
      s = MFMA16(qf1, k1f, s);
      sc[nf] = s;
    }

    // online softmax (rows r = quad*4+i, cols nf*16+l15)
    float p[4][4];
#pragma unroll
    for (int i=0;i<4;++i){
      float mt = -INFINITY;
#pragma unroll
      for (int nf=0;nf<4;++nf){
        const float sv = vk[nf] ? sc[nf][i]*0.125f : -INFINITY;
        p[nf][i] = sv;                        // reuse as scaled score
        mt = fmaxf(mt, sv);
      }
      for (int off=1; off<16; off<<=1) mt = fmaxf(mt, __shfl_xor(mt, off));
      const float mnew  = fmaxf(m_run[i], mt);
      const float alpha = (mnew == -INFINITY) ? 1.f : __expf(m_run[i] - mnew);
      float rs = 0.f;
#pragma unroll
      for (int nf=0;nf<4;++nf){
        const float pv = vk[nf] ? __expf(p[nf][i] - mnew) : 0.f;
        p[nf][i] = pv; rs += pv;
      }
      for (int off=1; off<16; off<<=1) rs += __shfl_xor(rs, off);
      l_run[i] = l_run[i]*alpha + rs;
      m_run[i] = mnew;
#pragma unroll
      for (int nf=0;nf<4;++nf) of[nf][i] *= alpha;
    }
    // write P strip (bf16) to wave-private LDS
#pragma unroll
    for (int i=0;i<4;++i)
#pragma unroll
      for (int nf=0;nf<4;++nf)
        Pl[w][quad*4+i][nf*16+l15] = f2bf(p[nf][i]);
    __syncthreads();                          // P visible (and lgkm drained)

    // O += P V  (A = P strip, B = V via Vt)
    bf8 pa0 = *reinterpret_cast<const bf8*>(&Pl[w][l15][quad*8]);
    bf8 pa1 = *reinterpret_cast<const bf8*>(&Pl[w][l15][32+quad*8]);
#pragma unroll
    for (int nf=0;nf<4;++nf){
      bf8 vb0 = *reinterpret_cast<const bf8*>(&Vt[nf*16+l15][quad*8]);
      bf8 vb1 = *reinterpret_cast<const bf8*>(&Vt[nf*16+l15][32+quad*8]);
      of[nf] = MFMA16(pa0, vb0, of[nf]);
      of[nf] = MFMA16(pa1, vb1, of[nf]);
    }
  }

  // epilogue: normalize, mask invalid query rows, bf16 store
#pragma unroll
  for (int i=0;i<4;++i){
    const int q = qs + quad*4 + i;
    const bool qv = (mb[q] != 0);
    const float inv = (qv && l_run[i] > 0.f) ? 1.f/l_run[i] : 0.f;
#pragma unroll
    for (int nf=0;nf<4;++nf)
      O[((size_t)bh*SEQ + q)*HDIM + nf*16 + l15] = f2bf(of[nf][i]*inv);
  }
}

// ---------------------------------------------------------------------------
// MFMA GEMM C: out = Ob @ WoutT^T  (M=8192,N=512,K=512), fp32 output.
// ---------------------------------------------------------------------------
__global__ __launch_bounds__(256) void gemm_out_mfma(
    const unsigned short* __restrict__ A,   // [8192][512] bf16 (Ob flat)
    const unsigned short* __restrict__ Bt,  // [512][512] bf16 (Wout^T)
    float* __restrict__ Out)
{
  __shared__ unsigned short As[128][72];
  __shared__ unsigned short Bs[128][72];
  const int t = threadIdx.x;
  const int w = t>>6, lane = t&63, quad = lane>>4, l15 = lane&15;
  const int wr = (w>>1)<<6, wc = (w&1)<<6;
  const int m0 = blockIdx.y<<7, n0 = blockIdx.x<<7;
  const int row = t>>3, seg = t&7;
  const unsigned short* Agp = A  + (size_t)(m0+row)*DMODEL + seg*8;
  const unsigned short* Bgp = Bt + (size_t)(n0+row)*DMODEL + seg*8;
  uint4 ga[4], gb[4];
#pragma unroll
  for (int p=0;p<4;++p){
    ga[p] = *reinterpret_cast<const uint4*>(Agp + (size_t)p*32*DMODEL);
    gb[p] = *reinterpret_cast<const uint4*>(Bgp + (size_t)p*32*DMODEL);
  }
  f32x4 acc[4][4];
#pragma unroll
  for (int i=0;i<4;++i)
#pragma unroll
    for (int j=0;j<4;++j) acc[i][j] = (f32x4){0.f,0.f,0.f,0.f};

  for (int k0=0;k0<DMODEL;k0+=64){
    __syncthreads();
#pragma unroll
    for (int p=0;p<4;++p){
      *reinterpret_cast<uint4*>(&As[row+p*32][seg*8]) = ga[p];
      *reinterpret_cast<uint4*>(&Bs[row+p*32][seg*8]) = gb[p];
    }
    __syncthreads();
    if (k0+64 < DMODEL){
#pragma unroll
      for (int p=0;p<4;++p){
        ga[p] = *reinterpret_cast<const uint4*>(Agp + (size_t)p*32*DMODEL + k0+64);
        gb[p] = *reinterpret_cast<const uint4*>(Bgp + (size_t)p*32*DMODEL + k0+64);
      }
    }
#pragma unroll
    for (int ks=0;ks<2;++ks){
      bf8 af[4], bfr[4];
#pragma unroll
      for (int mi=0;mi<4;++mi)
        af[mi]  = *reinterpret_cast<const bf8*>(&As[wr+mi*16+l15][ks*32+quad*8]);
#pragma unroll
      for (int nj=0;nj<4;++nj)
        bfr[nj] = *reinterpret_cast<const bf8*>(&Bs[wc+nj*16+l15][ks*32+quad*8]);
#pragma unroll
      for (int mi=0;mi<4;++mi)
#pragma unroll
        for (int nj=0;nj<4;++nj) acc[mi][nj] = MFMA16(af[mi], bfr[nj], acc[mi][nj]);
    }
  }
#pragma unroll
  for (int mi=0;mi<4;++mi)
#pragma unroll
    for (int i=0;i<4;++i){
      const int m = m0 + wr + mi*16 + quad*4 + i;
#pragma unroll
      for (int nj=0;nj<4;++nj)
        Out[(size_t)m*DMODEL + n0 + wc + nj*16 + l15] = acc[mi][nj][i];
    }
}

// ---------------------------------------------------------------------------
extern "C" void kernel_launch(void* const* d_in, const int* in_sizes, int n_in,
                              void* d_out, int out_size, void* d_ws, size_t ws_size,
                              hipStream_t stream) {
  (void)in_sizes; (void)n_in; (void)out_size; (void)ws_size;
  const float* x     = (const float*)d_in[0];
  const int*   pmask = (const int*)d_in[2];
  const float* Wqkv  = (const float*)d_in[3];
  const float* Wout  = (const float*)d_in[4];
  float* out = (float*)d_out;

  const size_t per = (size_t)BATCH*NHEADS*SEQ*HDIM;     // 4,194,304
  unsigned short* Xh    = (unsigned short*)d_ws;        // 8192*512
  unsigned short* WqkvT = Xh    + (size_t)8192*512;     // 1536*512
  unsigned short* WoutT = WqkvT + (size_t)1536*512;     // 512*512
  unsigned short* Qb    = WoutT + (size_t)512*512;
  unsigned short* Kb    = Qb + per;
  unsigned short* Vb    = Kb + per;
  unsigned short* Ob    = Vb + per;                     // ~44 MB total

  cast_x<<<2048, 256, 0, stream>>>(x, Xh);
  transpose_cast<<<dim3(QKV_N/64, DMODEL/64), 256, 0, stream>>>(Wqkv, WqkvT, DMODEL, QKV_N);
  transpose_cast<<<dim3(DMODEL/64, DMODEL/64), 256, 0, stream>>>(Wout, WoutT, DMODEL, DMODEL);

  gemm_qkv_mfma<<<dim3(QKV_N/128, 8192/128), 256, 0, stream>>>(Xh, WqkvT, Qb, Kb, Vb);
  attn_mfma<<<dim3(SEQ/64, BATCH*NHEADS), 256, 0, stream>>>(Qb, Kb, Vb, pmask, Ob);
  gemm_out_mfma<<<dim3(DMODEL/128, 8192/128), 256, 0, stream>>>(Ob, WoutT, out);
}